// Round 3
// baseline (406.682 us; speedup 1.0000x reference)
//
#include <hip/hip_runtime.h>
#include <math.h>

#define B 64
#define T 4096
#define D 256
#define U 256

typedef __attribute__((ext_vector_type(8)))  short s16x8;
typedef __attribute__((ext_vector_type(16))) float f32x16;

#define MT 32                 // rows per m-step
#define SPB 32                // m-steps per block
#define NBLK ((B*T)/(MT*SPB)) // 256 blocks = 1/CU; 4 blocks per batch b
#define LDAP 33               // padded m-stride (uint4 units) per k8-row

// DPP cross-lane add (VALU pipe, not LDS): v += lane-permuted v
#define DPP_ADD(v, ctrl)                                                     \
  v += __int_as_float(__builtin_amdgcn_update_dpp(                           \
      0, __float_as_int(v), ctrl, 0xF, 0xF, true))

// convert one thread's staged float4x4 row-chunk to hi/lo bf16, write LDS
__device__ __forceinline__ void stage_tile(uint4* bufH, uint4* bufL,
                                           const float4* rg, int sm, int sc0) {
#pragma unroll
  for (int i = 0; i < 4; ++i) {
    const float4 a = rg[i];
    const int k  = 4 * (sc0 + 16 * i);
    const int k8 = k >> 3;
    const int off = (k >> 2) & 1;
    const unsigned int ux = __float_as_uint(a.x), uy = __float_as_uint(a.y);
    const unsigned int uz = __float_as_uint(a.z), uw = __float_as_uint(a.w);
    const uint2 hi2 = make_uint2((ux >> 16) | (uy & 0xffff0000u),
                                 (uz >> 16) | (uw & 0xffff0000u));
    const float lx = a.x - __uint_as_float(ux & 0xffff0000u);
    const float ly = a.y - __uint_as_float(uy & 0xffff0000u);
    const float lz = a.z - __uint_as_float(uz & 0xffff0000u);
    const float lw = a.w - __uint_as_float(uw & 0xffff0000u);
    const uint2 lo2 = make_uint2(
        (__float_as_uint(lx) >> 16) | (__float_as_uint(ly) & 0xffff0000u),
        (__float_as_uint(lz) >> 16) | (__float_as_uint(lw) & 0xffff0000u));
    ((uint2*)&bufH[k8 * LDAP + sm])[off] = hi2;
    ((uint2*)&bufL[k8 * LDAP + sm])[off] = lo2;
  }
}

// lag-1 weight + context accumulate: w from red[], A-rows re-read from the
// (still-live) LDS tile, hi-bf16 only (softmax is flat -> error fully damped)
__device__ __forceinline__ void wctx_accum(
    const float (*redp)[8], const uint4* bufH, size_t rowb,
    int sm, int sc0, float* __restrict__ w_out, float* acc, float& zacc) {
  const float4* rp = (const float4*)&redp[sm][0];
  const float4 ra = rp[0], rb = rp[1];
  const float s8 = ra.x + ra.y + ra.z + ra.w + rb.x + rb.y + rb.z + rb.w;
  const float w = __expf(s8);                     // bounded: |s| <= ~13
  if (sc0 == 0) { w_out[rowb + sm] = w; zacc += w; }
#pragma unroll
  for (int i = 0; i < 4; ++i) {
    const int c = sc0 + 16 * i;
    const uint2 h = ((const uint2*)&bufH[(c >> 1) * LDAP + sm])[c & 1];
    const float x0 = __uint_as_float(h.x << 16);
    const float x1 = __uint_as_float(h.x & 0xffff0000u);
    const float x2 = __uint_as_float(h.y << 16);
    const float x3 = __uint_as_float(h.y & 0xffff0000u);
    acc[4 * i + 0] = fmaf(w, x0, acc[4 * i + 0]);
    acc[4 * i + 1] = fmaf(w, x1, acc[4 * i + 1]);
    acc[4 * i + 2] = fmaf(w, x2, acc[4 * i + 2]);
    acc[4 * i + 3] = fmaf(w, x3, acc[4 * i + 3]);
  }
}

// ============ fused scores + online context, 1 barrier per step =============
// Triple-buffered LDS tiles: interval k does wctx(k-1) [buf prv], MFMA(k)
// [buf cur], stage-write(k+1) [buf nxt] -- all disjoint, so ONE barrier per
// step orders everything.  stage+prefetch sit between the MFMA halves so the
// scheduler fills the matrix-pipe shadow with them.
__global__ __launch_bounds__(512, 2) void scores_ctx_kernel(
    const float* __restrict__ A,    // [B*T, D]
    const float* __restrict__ W1,   // [D, U]
    const float* __restrict__ W2,   // [D, U]
    const float* __restrict__ v,    // [U]
    float* __restrict__ w_out,      // [B*T] unnormalized weights e^s
    float* __restrict__ part,       // [NBLK][D] ctx partials (unnormalized)
    float* __restrict__ zpart)      // [NBLK] sum of w over block's rows
{
  __shared__ uint4 AH3[3][32 * LDAP];
  __shared__ uint4 AL3[3][32 * LDAP];
  __shared__ float red[2][32][8];      // [parity][row][wave] score partials
  __shared__ float wavebuf[8][16][16]; // block-end ctx reduction
  __shared__ float zred[8];

  const int tid  = threadIdx.x;
  const int lane = tid & 63;
  const int wv   = tid >> 6;        // 0..7
  const int l31  = lane & 31;
  const int half = lane >> 5;

  // ---- register-resident B-fragments from W1+W2 (once per block) ----
  const int n = wv * 32 + l31;
  s16x8 Bh[16], Bl[16];
#pragma unroll
  for (int s = 0; s < 16; ++s) {
    s16x8 bh, bl;
#pragma unroll
    for (int j = 0; j < 8; ++j) {
      const int k = s * 16 + half * 8 + j;
      const float w = W1[k * 256 + n] + W2[k * 256 + n];
      const unsigned int uw = __float_as_uint(w);
      const float wl = w - __uint_as_float(uw & 0xffff0000u);
      bh[j] = (short)(uw >> 16);
      bl[j] = (short)(__float_as_uint(wl) >> 16);
    }
    Bh[s] = bh; Bl[s] = bl;
  }
  const float vv = v[n];

  // staging map: thread -> (row sm, float4-chunk sc0 + 16*i)
  const int sm  = tid >> 4;   // 0..31
  const int sc0 = tid & 15;

  float acc[16];
#pragma unroll
  for (int q = 0; q < 16; ++q) acc[q] = 0.f;
  float zacc = 0.f;

  const size_t row0 = (size_t)blockIdx.x * (MT * SPB);
  float4 rg[4];
  {
    const float4* src = (const float4*)(A + (row0 + sm) * 256);
#pragma unroll
    for (int i = 0; i < 4; ++i) rg[i] = src[sc0 + 16 * i];
  }
  stage_tile(AH3[0], AL3[0], rg, sm, sc0);
  {
    const float4* src = (const float4*)(A + (row0 + MT + sm) * 256);
#pragma unroll
    for (int i = 0; i < 4; ++i) rg[i] = src[sc0 + 16 * i];
  }
  __syncthreads();

  int cur = 0;
  for (int step = 0; step < SPB; ++step) {
    const int nxt = (cur == 2) ? 0 : cur + 1;
    const int prv = (nxt == 2) ? 0 : nxt + 1;   // = cur - 1 mod 3
    const int par = step & 1;

    // ---- wctx for step-1 (red + tile from last interval) ----
    if (step > 0)
      wctx_accum(red[par ^ 1], AH3[prv], row0 + (size_t)(step - 1) * MT,
                 sm, sc0, w_out, acc, zacc);

    // ---- MFMA half 1 ----
    f32x16 a0 = {}, a1 = {};
    const uint4* cH = AH3[cur];
    const uint4* cL = AL3[cur];
#pragma unroll
    for (int s = 0; s < 8; ++s) {
      const uint4 qh = cH[(2 * s + half) * LDAP + l31];
      const uint4 ql = cL[(2 * s + half) * LDAP + l31];
      const s16x8 ah = __builtin_bit_cast(s16x8, qh);
      const s16x8 al = __builtin_bit_cast(s16x8, ql);
      a0 = __builtin_amdgcn_mfma_f32_32x32x16_bf16(ah, Bh[s], a0, 0, 0, 0);
      a1 = __builtin_amdgcn_mfma_f32_32x32x16_bf16(ah, Bl[s], a1, 0, 0, 0);
      a1 = __builtin_amdgcn_mfma_f32_32x32x16_bf16(al, Bh[s], a1, 0, 0, 0);
    }

    // ---- stage next tile + issue prefetch (fills MFMA shadow) ----
    if (step + 1 < SPB) stage_tile(AH3[nxt], AL3[nxt], rg, sm, sc0);
    if (step + 2 < SPB) {
      const float4* src =
          (const float4*)(A + (row0 + (size_t)(step + 2) * MT + sm) * 256);
#pragma unroll
      for (int i = 0; i < 4; ++i) rg[i] = src[sc0 + 16 * i];
    }

    // ---- MFMA half 2 ----
#pragma unroll
    for (int s = 8; s < 16; ++s) {
      const uint4 qh = cH[(2 * s + half) * LDAP + l31];
      const uint4 ql = cL[(2 * s + half) * LDAP + l31];
      const s16x8 ah = __builtin_bit_cast(s16x8, qh);
      const s16x8 al = __builtin_bit_cast(s16x8, ql);
      a0 = __builtin_amdgcn_mfma_f32_32x32x16_bf16(ah, Bh[s], a0, 0, 0, 0);
      a1 = __builtin_amdgcn_mfma_f32_32x32x16_bf16(ah, Bl[s], a1, 0, 0, 0);
      a1 = __builtin_amdgcn_mfma_f32_32x32x16_bf16(al, Bh[s], a1, 0, 0, 0);
    }

    // ---- epilogue: tanh, *v[u], reduce wave's 32 cols (DPP) ----
#pragma unroll
    for (int r = 0; r < 16; ++r) {
      const float x = a0[r] + a1[r];
      const float e = __expf(x + x);                     // e^{2x}
      float p = (1.f - 2.f * __builtin_amdgcn_rcpf(e + 1.f)) * vv;  // tanh*v
      DPP_ADD(p, 0xB1);   // + lane^1
      DPP_ADD(p, 0x4E);   // + lane^2
      DPP_ADD(p, 0x141);  // row_half_mirror: 8-sum
      DPP_ADD(p, 0x140);  // row_mirror: 16-sum
      p += __int_as_float(
          __builtin_amdgcn_ds_swizzle(__float_as_int(p), 0x401F));  // xor16
      if (l31 == 0)
        red[par][(r & 3) + 8 * (r >> 2) + 4 * half][wv] = p;
    }
    __syncthreads();
    cur = nxt;
  }

  // ---- drain: wctx for the last step ----
  wctx_accum(red[(SPB - 1) & 1], AH3[(SPB - 1) % 3],
             row0 + (size_t)(SPB - 1) * MT, sm, sc0, w_out, acc, zacc);

  // ---- block-end reductions ----
#pragma unroll
  for (int q = 0; q < 16; ++q) {
    float p = acc[q];
    p += __shfl_xor(p, 16);
    p += __shfl_xor(p, 32);
    acc[q] = p;
  }
  if (lane < 16) {
#pragma unroll
    for (int q = 0; q < 16; ++q) wavebuf[wv][lane][q] = acc[q];
  }
  {
    float z = zacc;                    // nonzero only where sc0==0
    z += __shfl_xor(z, 16);
    z += __shfl_xor(z, 32);
    if (lane == 0) zred[wv] = z;
  }
  __syncthreads();

  if (tid < 256) {
    // d = tid:  sc = (d&63)>>2, q = 4*(d>>6) + (d&3)
    const int sc = (tid & 63) >> 2;
    const int q  = 4 * (tid >> 6) + (tid & 3);
    float ssum = 0.f;
#pragma unroll
    for (int wvi = 0; wvi < 8; ++wvi) ssum += wavebuf[wvi][sc][q];
    part[blockIdx.x * 256 + tid] = ssum;
  }
  if (tid == 0) {
    float zz = 0.f;
#pragma unroll
    for (int i = 0; i < 8; ++i) zz += zred[i];
    zpart[blockIdx.x] = zz;
  }
}

// ============ finalize: Z per batch, scale ctx + attn =======================
#define BPB (NBLK / B)   // blocks per batch = 4
__global__ __launch_bounds__(1024) void finalize_kernel(
    const float* __restrict__ part,   // [NBLK][D] = [B*BPB][D]
    const float* __restrict__ zpart,  // [NBLK]
    float* __restrict__ attn,         // [B*T] in: w, out: w/Z
    float* __restrict__ ctx)          // [B*D]
{
  const int b = blockIdx.x;
  const int tid = threadIdx.x;
  __shared__ float shinv;
  if (tid == 0) {
    float z = 0.f;
#pragma unroll
    for (int c = 0; c < BPB; ++c) z += zpart[b * BPB + c];
    shinv = 1.0f / z;
  }
  __syncthreads();
  const float iz = shinv;

  if (tid < D) {
    float s = 0.f;
#pragma unroll
    for (int c = 0; c < BPB; ++c) s += part[(b * BPB + c) * D + tid];
    ctx[b * D + tid] = s * iz;
  }

  float4* row = (float4*)(attn + (long)b * T);
  float4 w4 = row[tid];                 // 1024 threads * 4 = T
  w4.x *= iz; w4.y *= iz; w4.z *= iz; w4.w *= iz;
  row[tid] = w4;
}

extern "C" void kernel_launch(void* const* d_in, const int* in_sizes, int n_in,
                              void* d_out, int out_size, void* d_ws, size_t ws_size,
                              hipStream_t stream) {
    const float* lstm = (const float*)d_in[0];  // [B,T,D]
    const float* W1   = (const float*)d_in[1];  // [D,U]
    const float* W2   = (const float*)d_in[2];  // [D,U]
    const float* v    = (const float*)d_in[3];  // [U,1]

    float* out  = (float*)d_out;
    float* ctx  = out;            // [B*D]
    float* attn = out + B * D;    // [B*T]

    float* part  = (float*)d_ws;          // NBLK*D floats = 256 KB
    float* zpart = part + NBLK * D;       // NBLK floats

    scores_ctx_kernel<<<NBLK, 512, 0, stream>>>(lstm, W1, W2, v, attn, part, zpart);
    finalize_kernel<<<B, 1024, 0, stream>>>(part, zpart, attn, ctx);
}